// Round 2
// baseline (821.553 us; speedup 1.0000x reference)
//
#include <hip/hip_runtime.h>
#include <hip/hip_bf16.h>

#define NN 4096
#define EE 2048
#define RR 4
#define FF 128
#define HDD 256

typedef __attribute__((ext_vector_type(4))) float floatx4;
typedef __attribute__((ext_vector_type(8))) __bf16 bf16x8;

#define AS1 __attribute__((address_space(1)))
#define AS3 __attribute__((address_space(3)))

__device__ __forceinline__ void async16(const void* g, void* l) {
  // global -> LDS direct copy, 16B per lane; LDS dest = wave-uniform base + lane*16
  __builtin_amdgcn_global_load_lds((const AS1 void*)(unsigned long long)(g),
                                   (AS3 void*)(unsigned int)(unsigned long long)(l),
                                   16, 0, 0);
}

__device__ inline unsigned short f2b(float x) {
  unsigned int u = __float_as_uint(x);
  unsigned int r = u + 0x7fffu + ((u >> 16) & 1u);
  return (unsigned short)(r >> 16);
}

// ---------------- prep: softmax(rel_attn), sigmoid(imp) ----------------
__global__ void k_prep(const float* rel, const float* imp, float* rw, float* sig) {
  if (threadIdx.x == 0) {
    float m = -1e30f;
    for (int r = 0; r < RR; r++) m = fmaxf(m, rel[r]);
    float e[RR], s = 0.f;
    for (int r = 0; r < RR; r++) { e[r] = expf(rel[r] - m); s += e[r]; }
    for (int r = 0; r < RR; r++) rw[r] = e[r] / s;
    for (int i = 0; i < 3 * RR; i++) sig[i] = 1.0f / (1.0f + expf(-imp[i]));
  }
}

// ---- single pass over H: row sums -> dvs[r][n] = rw*rsqrt(rw*sum+eps), plus 0/1 bitmask ----
__global__ void k_dvmask(const float* __restrict__ H, const float* __restrict__ rw,
                         float* __restrict__ dvs, unsigned long long* __restrict__ mask) {
  int wave = (blockIdx.x << 2) | (threadIdx.x >> 6);  // = r*NN + n
  int lane = threadIdx.x & 63;
  int r = wave >> 12;
  const float* row = H + (size_t)wave * EE;
  unsigned long long* mrow = mask + (size_t)wave * (EE / 64);
  float s = 0.f;
  for (int j = 0; j < EE / 64; j++) {
    float h = row[j * 64 + lane];
    s += h;
    unsigned long long m = __ballot(h != 0.0f);
    if (lane == 0) mrow[j] = m;
  }
  for (int off = 32; off; off >>= 1) s += __shfl_down(s, off);
  if (lane == 0) {
    float rwr = rw[r];
    dvs[wave] = rwr * rsqrtf(rwr * s + 1e-8f);
  }
}

// ---- column degrees from the bitmask: de[r][e] = rsqrt(rw*colsum+eps) ----
__global__ void k_de_bits(const unsigned long long* __restrict__ mask, const float* __restrict__ rw,
                          float* __restrict__ de) {
  int e = blockIdx.x * 256 + threadIdx.x;
  int r = blockIdx.y;
  const unsigned long long* mb = mask + (size_t)r * NN * (EE / 64) + (e >> 6);
  int sh = e & 63;
  int s = 0;
#pragma unroll 8
  for (int n = 0; n < NN; n++) s += (int)((mb[(size_t)n * (EE / 64)] >> sh) & 1ULL);
  de[r * EE + e] = rsqrtf(rw[r] * (float)s + 1e-8f);
}

// ---- build theta[r][n][e] bf16 and thetaT[r][e][n] from bitmask ----
__global__ void k_build_theta_bits(const unsigned long long* __restrict__ mask,
                                   const float* __restrict__ dvs, const float* __restrict__ de,
                                   unsigned short* __restrict__ theta, unsigned short* __restrict__ thetaT) {
  __shared__ unsigned short tile[64][65];
  int r = blockIdx.z;
  int e0 = blockIdx.x * 64, n0 = blockIdx.y * 64;
  int tr = threadIdx.x >> 4, tc = threadIdx.x & 15;
  float de0 = de[r * EE + e0 + tc * 4 + 0];
  float de1 = de[r * EE + e0 + tc * 4 + 1];
  float de2 = de[r * EE + e0 + tc * 4 + 2];
  float de3 = de[r * EE + e0 + tc * 4 + 3];
  int wcol = e0 >> 6;
#pragma unroll
  for (int i = 0; i < 4; i++) {
    int n = n0 + tr + 16 * i;
    unsigned long long w = mask[((size_t)r * NN + n) * (EE / 64) + wcol];
    float d = dvs[r * NN + n];
    unsigned short b0 = ((w >> (tc * 4 + 0)) & 1) ? f2b(d * de0) : 0;
    unsigned short b1 = ((w >> (tc * 4 + 1)) & 1) ? f2b(d * de1) : 0;
    unsigned short b2 = ((w >> (tc * 4 + 2)) & 1) ? f2b(d * de2) : 0;
    unsigned short b3 = ((w >> (tc * 4 + 3)) & 1) ? f2b(d * de3) : 0;
    ushort4 o; o.x = b0; o.y = b1; o.z = b2; o.w = b3;
    *(ushort4*)(theta + ((size_t)r * NN + n) * EE + e0 + tc * 4) = o;
    tile[tr + 16 * i][tc * 4 + 0] = b0;
    tile[tr + 16 * i][tc * 4 + 1] = b1;
    tile[tr + 16 * i][tc * 4 + 2] = b2;
    tile[tr + 16 * i][tc * 4 + 3] = b3;
  }
  __syncthreads();
#pragma unroll
  for (int i = 0; i < 4; i++) {
    int e = e0 + tr + 16 * i;
    ushort4 o;
    o.x = tile[tc * 4 + 0][tr + 16 * i];
    o.y = tile[tc * 4 + 1][tr + 16 * i];
    o.z = tile[tc * 4 + 2][tr + 16 * i];
    o.w = tile[tc * 4 + 3][tr + 16 * i];
    *(ushort4*)(thetaT + ((size_t)r * EE + e) * NN + n0 + tc * 4) = o;
  }
}

// ---- flat f32 -> bf16 ----
__global__ void k_cvt(const float* __restrict__ src, unsigned short* __restrict__ dst) {
  int i = (blockIdx.x * 256 + threadIdx.x) * 4;
  float4 v = *(const float4*)(src + i);
  ushort4 o; o.x = f2b(v.x); o.y = f2b(v.y); o.z = f2b(v.z); o.w = f2b(v.w);
  *(ushort4*)(dst + i) = o;
}

// ---- f32 [Z][M][C] -> bf16 [Z][C][M] (transpose) ----
__global__ void k_cvtT(const float* __restrict__ src, unsigned short* __restrict__ dst, int M, int C) {
  __shared__ unsigned short tile[64][65];
  int z = blockIdx.z;
  int c0 = blockIdx.x * 64, m0 = blockIdx.y * 64;
  const float* s = src + (size_t)z * M * C;
  unsigned short* d = dst + (size_t)z * M * C;
  int tr = threadIdx.x >> 4, tc = threadIdx.x & 15;
#pragma unroll
  for (int i = 0; i < 4; i++) {
    int m = m0 + tr + 16 * i;
    float4 v = *(const float4*)(s + (size_t)m * C + c0 + tc * 4);
    tile[tr + 16 * i][tc * 4 + 0] = f2b(v.x);
    tile[tr + 16 * i][tc * 4 + 1] = f2b(v.y);
    tile[tr + 16 * i][tc * 4 + 2] = f2b(v.z);
    tile[tr + 16 * i][tc * 4 + 3] = f2b(v.w);
  }
  __syncthreads();
#pragma unroll
  for (int i = 0; i < 4; i++) {
    int c = c0 + tr + 16 * i;
    ushort4 v;
    v.x = tile[tc * 4 + 0][tr + 16 * i];
    v.y = tile[tc * 4 + 1][tr + 16 * i];
    v.z = tile[tc * 4 + 2][tr + 16 * i];
    v.w = tile[tc * 4 + 3][tr + 16 * i];
    *(ushort4*)(d + (size_t)c * M + m0 + tc * 4) = v;
  }
}

// ---- bf16 [M][C] -> bf16 [C][M] ----
__global__ void k_tr(const unsigned short* __restrict__ src, unsigned short* __restrict__ dst, int M, int C) {
  __shared__ unsigned short tile[64][65];
  int c0 = blockIdx.x * 64, m0 = blockIdx.y * 64;
  int tr = threadIdx.x >> 4, tc = threadIdx.x & 15;
#pragma unroll
  for (int i = 0; i < 4; i++) {
    int m = m0 + tr + 16 * i;
    ushort4 v = *(const ushort4*)(src + (size_t)m * C + c0 + tc * 4);
    tile[tr + 16 * i][tc * 4 + 0] = v.x;
    tile[tr + 16 * i][tc * 4 + 1] = v.y;
    tile[tr + 16 * i][tc * 4 + 2] = v.z;
    tile[tr + 16 * i][tc * 4 + 3] = v.w;
  }
  __syncthreads();
#pragma unroll
  for (int i = 0; i < 4; i++) {
    int c = c0 + tr + 16 * i;
    ushort4 v;
    v.x = tile[tc * 4 + 0][tr + 16 * i];
    v.y = tile[tc * 4 + 1][tr + 16 * i];
    v.z = tile[tc * 4 + 2][tr + 16 * i];
    v.w = tile[tc * 4 + 3][tr + 16 * i];
    *(ushort4*)(dst + (size_t)c * M + m0 + tc * 4) = v;
  }
}

// ---- W1catT[o][r*FF+f] = sig*W1[r][f][o] ----
__global__ void k_wcat(const float* __restrict__ W, const float* __restrict__ sig, int loff, int Fin,
                       unsigned short* __restrict__ WT) {
  int idx = blockIdx.x * 256 + threadIdx.x;
  int o = idx % HDD;
  int f = (idx / HDD) % Fin;
  int r = idx / (HDD * Fin);
  WT[(size_t)o * (RR * Fin) + r * Fin + f] = f2b(sig[loff + r] * W[((size_t)r * Fin + f) * HDD + o]);
}

// ---- WT[r][o][c] = sig*W[r][c][o] ----
__global__ void k_wt(const float* __restrict__ W, const float* __restrict__ sig, int loff,
                     int Cin, int Cout, unsigned short* __restrict__ WT) {
  int idx = blockIdx.x * 256 + threadIdx.x;
  int c = idx % Cin;
  int o = (idx / Cin) % Cout;
  int r = idx / (Cin * Cout);
  WT[idx] = f2b(sig[loff + r] * W[((size_t)r * Cin + c) * Cout + o]);
}

// ---------------- MFMA GEMM, 64x64 tile, BK=64, async LDS staging, split-K ----------------
// C[64x64 tile] (+)= A[M x K] * BT[N x K]^T  for z = rz*SK + kz (rel, k-chunk)
// LDS k-major cells: cell(kg,row) at elem kg*520 + row*8 (16B pad per kgroup -> conflict-free b128)
// mode 0: plain f32 store (SK==1 only); mode 1: atomicAdd f32 (caller memsets C)
__global__ __launch_bounds__(256) void k_gemm2(
    const unsigned short* __restrict__ A, const unsigned short* __restrict__ BT,
    int K, int lda, int ldb, long a_rs, long b_rs,
    int SK, int mode, float* __restrict__ C, long c_rel, int ldc) {
  __shared__ unsigned short Al[8 * 520];
  __shared__ unsigned short Bl[8 * 520];
  int tid = threadIdx.x, wid = tid >> 6, lane = tid & 63;
  int m0 = blockIdx.x << 6, n0 = blockIdx.y << 6;
  int rz = blockIdx.z / SK, kz = blockIdx.z - rz * SK;
  int Kc = K / SK;
  const unsigned short* Ab = A + (size_t)rz * a_rs + (size_t)(m0 + lane) * lda + (size_t)kz * Kc;
  const unsigned short* Bb = BT + (size_t)rz * b_rs + (size_t)(n0 + lane) * ldb + (size_t)kz * Kc;
  int wm = (wid >> 1) << 5, wn = (wid & 1) << 5;
  int fm = lane & 15, quad = lane >> 4;
  floatx4 acc[2][2];
#pragma unroll
  for (int i = 0; i < 2; i++)
#pragma unroll
    for (int j = 0; j < 2; j++) acc[i][j] = (floatx4){0.f, 0.f, 0.f, 0.f};
  int c0 = wid, c1 = wid + 4;
  for (int k0 = 0; k0 < Kc; k0 += 64) {
    async16(Ab + k0 + c0 * 8, &Al[c0 * 520]);
    async16(Ab + k0 + c1 * 8, &Al[c1 * 520]);
    async16(Bb + k0 + c0 * 8, &Bl[c0 * 520]);
    async16(Bb + k0 + c1 * 8, &Bl[c1 * 520]);
    __syncthreads();  // compiler drains vmcnt before s_barrier -> LDS writes visible
#pragma unroll
    for (int ks = 0; ks < 2; ks++) {
      int kg = (ks * 4 + quad) * 520;
      bf16x8 a0 = *(const bf16x8*)&Al[kg + (wm + fm) * 8];
      bf16x8 a1 = *(const bf16x8*)&Al[kg + (wm + 16 + fm) * 8];
      bf16x8 b0 = *(const bf16x8*)&Bl[kg + (wn + fm) * 8];
      bf16x8 b1 = *(const bf16x8*)&Bl[kg + (wn + 16 + fm) * 8];
      acc[0][0] = __builtin_amdgcn_mfma_f32_16x16x32_bf16(a0, b0, acc[0][0], 0, 0, 0);
      acc[0][1] = __builtin_amdgcn_mfma_f32_16x16x32_bf16(a0, b1, acc[0][1], 0, 0, 0);
      acc[1][0] = __builtin_amdgcn_mfma_f32_16x16x32_bf16(a1, b0, acc[1][0], 0, 0, 0);
      acc[1][1] = __builtin_amdgcn_mfma_f32_16x16x32_bf16(a1, b1, acc[1][1], 0, 0, 0);
    }
    __syncthreads();
  }
  float* Cb = C + (size_t)rz * c_rel;
#pragma unroll
  for (int mi = 0; mi < 2; mi++)
#pragma unroll
    for (int ni = 0; ni < 2; ni++)
#pragma unroll
      for (int v = 0; v < 4; v++) {
        int row = m0 + wm + mi * 16 + quad * 4 + v;
        int col = n0 + wn + ni * 16 + fm;
        float val = acc[mi][ni][v];
        float* p = Cb + (size_t)row * ldc + col;
        if (mode) atomicAdd(p, val);
        else *p = val;
      }
}

// ---- column stats over [NN][HDD] f32 ----
__global__ void k_colstats(const float* __restrict__ x, float* __restrict__ cs, float* __restrict__ cs2) {
  int col = threadIdx.x;
  int row0 = blockIdx.y * 64;
  float s = 0.f, s2 = 0.f;
  for (int i = 0; i < 64; i++) {
    float v = x[(size_t)(row0 + i) * HDD + col];
    s += v; s2 += v * v;
  }
  atomicAdd(&cs[col], s);
  atomicAdd(&cs2[col], s2);
}

// ---- BN (batch stats) -> LN -> ELU -> bf16 [NN][HDD] ----
__global__ void k_bnlnelu(const float* __restrict__ x, const float* __restrict__ cs, const float* __restrict__ cs2,
                          const float* __restrict__ bg, const float* __restrict__ bb,
                          const float* __restrict__ lg, const float* __restrict__ lb,
                          unsigned short* __restrict__ out) {
  int wid = threadIdx.x >> 6, lane = threadIdx.x & 63;
  int n = blockIdx.x * 4 + wid;
  float y[4];
  float m = 0.f;
#pragma unroll
  for (int j = 0; j < 4; j++) {
    int c = lane + 64 * j;
    float mu = cs[c] * (1.0f / NN);
    float var = cs2[c] * (1.0f / NN) - mu * mu;
    float xv = x[(size_t)n * HDD + c];
    y[j] = (xv - mu) * rsqrtf(var + 1e-5f) * bg[c] + bb[c];
    m += y[j];
  }
  for (int off = 32; off; off >>= 1) m += __shfl_down(m, off);
  m = __shfl(m, 0) * (1.0f / HDD);
  float var = 0.f;
#pragma unroll
  for (int j = 0; j < 4; j++) { float d = y[j] - m; var += d * d; }
  for (int off = 32; off; off >>= 1) var += __shfl_down(var, off);
  var = __shfl(var, 0) * (1.0f / HDD);
  float inv = rsqrtf(var + 1e-5f);
#pragma unroll
  for (int j = 0; j < 4; j++) {
    int c = lane + 64 * j;
    float z = (y[j] - m) * inv * lg[c] + lb[c];
    z = z > 0.f ? z : expm1f(z);
    out[(size_t)n * HDD + c] = f2b(z);
  }
}

// ---- d_out[n][f] = X[n][f] + b3[f] ----
__global__ void k_initout(const float* __restrict__ X, const float* __restrict__ b3, float* __restrict__ out) {
  int i = (blockIdx.x * 256 + threadIdx.x) * 4;
  float4 x = *(const float4*)(X + i);
  const float* b = b3 + (i & (FF - 1));
  float4 o; o.x = x.x + b[0]; o.y = x.y + b[1]; o.z = x.z + b[2]; o.w = x.w + b[3];
  *(float4*)(out + i) = o;
}

extern "C" void kernel_launch(void* const* d_in, const int* in_sizes, int n_in,
                              void* d_out, int out_size, void* d_ws, size_t ws_size,
                              hipStream_t stream) {
  const float* X   = (const float*)d_in[0];
  const float* H   = (const float*)d_in[1];
  const float* W1  = (const float*)d_in[2];
  const float* W2  = (const float*)d_in[3];
  const float* W3  = (const float*)d_in[4];
  const float* imp = (const float*)d_in[5];
  const float* b3  = (const float*)d_in[8];
  const float* bng = (const float*)d_in[9];
  const float* bnb = (const float*)d_in[10];
  const float* lng = (const float*)d_in[11];
  const float* lnb = (const float*)d_in[12];
  const float* rel = (const float*)d_in[13];
  (void)in_sizes; (void)n_in; (void)out_size; (void)ws_size;

  char* w = (char*)d_ws;
  size_t off = 0;
  auto alloc = [&](size_t bytes) -> void* {
    void* p = w + off;
    off += (bytes + 255) & ~(size_t)255;
    return p;
  };
  float* rw   = (float*)alloc(16);
  float* sig  = (float*)alloc(48);
  float* dvs  = (float*)alloc((size_t)RR * NN * 4);
  float* de   = (float*)alloc((size_t)RR * EE * 4);
  float* cs   = (float*)alloc(HDD * 4);
  float* cs2  = (float*)alloc(HDD * 4);
  unsigned long long* mask = (unsigned long long*)alloc((size_t)RR * NN * (EE / 64) * 8);
  unsigned short* theta  = (unsigned short*)alloc((size_t)RR * NN * EE * 2);
  unsigned short* thetaT = (unsigned short*)alloc((size_t)RR * NN * EE * 2);
  float* bufA = (float*)alloc((size_t)RR * EE * HDD * 4);           // 8MB f32
  float* bufB = (float*)alloc((size_t)RR * EE * HDD * 4);           // 8MB f32
  unsigned short* bufC = (unsigned short*)alloc((size_t)RR * EE * HDD * 2);  // 4MB bf16
  unsigned short* bufD = (unsigned short*)alloc((size_t)RR * EE * HDD * 2);  // 4MB bf16
  float* convout = (float*)alloc((size_t)NN * HDD * 4);             // 4MB
  unsigned short* Xb  = (unsigned short*)alloc((size_t)NN * HDD * 2);
  unsigned short* XbT = (unsigned short*)alloc((size_t)NN * HDD * 2);
  unsigned short* bufW = (unsigned short*)alloc((size_t)RR * HDD * HDD * 2); // 512KB

  // ---- prep ----
  k_prep<<<1, 64, 0, stream>>>(rel, imp, rw, sig);
  k_dvmask<<<(RR * NN) / 4, 256, 0, stream>>>(H, rw, dvs, mask);
  k_de_bits<<<dim3(EE / 256, RR), 256, 0, stream>>>(mask, rw, de);
  k_build_theta_bits<<<dim3(EE / 64, NN / 64, RR), 256, 0, stream>>>(mask, dvs, de, theta, thetaT);
  k_cvtT<<<dim3(FF / 64, NN / 64, 1), 256, 0, stream>>>(X, XbT, NN, FF);  // XbT = X^T bf16 [128][4096]

  // ---- layer 1 (128 -> 256) ----
  // tT[r][f][e] = sum_n X^T[f][n] thetaT[r][e][n]   (M=128,N=2048,K=4096, SK=4)
  hipMemsetAsync(bufA, 0, (size_t)RR * FF * EE * 4, stream);
  k_gemm2<<<dim3(FF / 64, EE / 64, RR * 4), 256, 0, stream>>>(
      XbT, thetaT, NN, NN, NN, 0, (long)EE * NN, 4, 1, bufA, (long)FF * EE, EE);
  k_cvt<<<(RR * FF * EE) / 1024, 256, 0, stream>>>(bufA, bufC);  // tTb
  // Hcat[n][r*128+f] = sum_e theta[r][n][e] tTb[r][f][e]   (M=4096,N=128,K=2048, SK=2)
  hipMemsetAsync(bufB, 0, (size_t)NN * RR * FF * 4, stream);
  k_gemm2<<<dim3(NN / 64, FF / 64, RR * 2), 256, 0, stream>>>(
      theta, bufC, EE, EE, EE, (long)NN * EE, (long)FF * EE, 2, 1, bufB, (long)FF, RR * FF);
  k_cvt<<<(NN * RR * FF) / 1024, 256, 0, stream>>>(bufB, bufD);  // Hcatb
  k_wcat<<<(RR * FF * HDD) / 256, 256, 0, stream>>>(W1, sig, 0, FF, bufW);
  // convout = Hcatb @ W1cat  (M=4096,N=256,K=512, SK=1, plain store; b1 dropped: BN-invariant)
  k_gemm2<<<dim3(NN / 64, HDD / 64, 1), 256, 0, stream>>>(
      bufD, bufW, RR * FF, RR * FF, RR * FF, 0, 0, 1, 0, convout, 0, HDD);
  hipMemsetAsync(cs, 0, HDD * 4, stream);
  hipMemsetAsync(cs2, 0, HDD * 4, stream);
  k_colstats<<<dim3(1, NN / 64), 256, 0, stream>>>(convout, cs, cs2);
  k_bnlnelu<<<NN / 4, 256, 0, stream>>>(convout, cs, cs2, bng, bnb, lng, lnb, Xb);
  k_tr<<<dim3(HDD / 64, NN / 64), 256, 0, stream>>>(Xb, XbT, NN, HDD);

  // ---- layer 2 (256 -> 256) ----
  // t[r][e][c] = sum_n thetaT[r][e][n] h^T[c][n]   (M=2048,N=256,K=4096, SK=4)
  hipMemsetAsync(bufA, 0, (size_t)RR * EE * HDD * 4, stream);
  k_gemm2<<<dim3(EE / 64, HDD / 64, RR * 4), 256, 0, stream>>>(
      thetaT, XbT, NN, NN, NN, (long)EE * NN, 0, 4, 1, bufA, (long)EE * HDD, HDD);
  k_cvt<<<(RR * EE * HDD) / 1024, 256, 0, stream>>>(bufA, bufD);  // t2b [r][e][c]
  k_wt<<<(RR * HDD * HDD) / 256, 256, 0, stream>>>(W2, sig, RR, HDD, HDD, bufW);  // W2T [r][o][c]
  // u[r][e][o] = sum_c t2b[r][e][c] W2T[r][o][c]   (M=2048,N=256,K=256, SK=1, store)
  k_gemm2<<<dim3(EE / 64, HDD / 64, RR), 256, 0, stream>>>(
      bufD, bufW, HDD, HDD, HDD, (long)EE * HDD, (long)HDD * HDD, 1, 0, bufB, (long)EE * HDD, HDD);
  k_cvtT<<<dim3(HDD / 64, EE / 64, RR), 256, 0, stream>>>(bufB, bufC, EE, HDD);  // uTb [r][o][e]
  // convout[n][o] = sum_r sum_e theta[r][n][e] uTb[r][o][e]   (M=4096,N=256,K=2048, rel-fused, SK=2)
  hipMemsetAsync(convout, 0, (size_t)NN * HDD * 4, stream);
  k_gemm2<<<dim3(NN / 64, HDD / 64, RR * 2), 256, 0, stream>>>(
      theta, bufC, EE, EE, EE, (long)NN * EE, (long)HDD * EE, 2, 1, convout, 0, HDD);
  hipMemsetAsync(cs, 0, HDD * 4, stream);
  hipMemsetAsync(cs2, 0, HDD * 4, stream);
  k_colstats<<<dim3(1, NN / 64), 256, 0, stream>>>(convout, cs, cs2);
  k_bnlnelu<<<NN / 4, 256, 0, stream>>>(convout, cs, cs2, bng + HDD, bnb + HDD, lng + HDD, lnb + HDD, Xb);

  // ---- layer 3 (256 -> 128), W3 applied first ----
  k_wt<<<(RR * HDD * FF) / 256, 256, 0, stream>>>(W3, sig, 2 * RR, HDD, FF, bufW);  // W3T [r][o][c]
  // y[r][n][o] = sum_c Xb[n][c] W3T[r][o][c]   (M=4096,N=128,K=256, SK=1, store)
  k_gemm2<<<dim3(NN / 64, FF / 64, RR), 256, 0, stream>>>(
      Xb, bufW, HDD, HDD, HDD, 0, (long)FF * HDD, 1, 0, bufA, (long)NN * FF, FF);
  k_cvtT<<<dim3(FF / 64, NN / 64, RR), 256, 0, stream>>>(bufA, bufD, NN, FF);  // yTb [r][f][n]
  // s[r][e][f] = sum_n thetaT[r][e][n] yTb[r][f][n]   (M=2048,N=128,K=4096, SK=4)
  hipMemsetAsync(bufB, 0, (size_t)RR * EE * FF * 4, stream);
  k_gemm2<<<dim3(EE / 64, FF / 64, RR * 4), 256, 0, stream>>>(
      thetaT, bufD, NN, NN, NN, (long)EE * NN, (long)FF * NN, 4, 1, bufB, (long)EE * FF, FF);
  k_cvtT<<<dim3(FF / 64, EE / 64, RR), 256, 0, stream>>>(bufB, bufC, EE, FF);  // sTb [r][f][e]
  k_initout<<<(NN * FF) / 1024, 256, 0, stream>>>(X, b3, (float*)d_out);
  // d_out[n][f] += sum_r sum_e theta[r][n][e] sTb[r][f][e]   (M=4096,N=128,K=2048, rel-fused, SK=2)
  k_gemm2<<<dim3(NN / 64, FF / 64, RR * 2), 256, 0, stream>>>(
      theta, bufC, EE, EE, EE, (long)NN * EE, (long)FF * EE, 2, 1, (float*)d_out, 0, FF);
}

// Round 3
// 729.756 us; speedup vs baseline: 1.1258x; 1.1258x over previous
//
#include <hip/hip_runtime.h>
#include <hip/hip_bf16.h>

#define NN 4096
#define EE 2048
#define RR 4
#define FF 128
#define HDD 256

typedef __attribute__((ext_vector_type(4))) float floatx4;
typedef __attribute__((ext_vector_type(8))) __bf16 bf16x8;

#define AS1 __attribute__((address_space(1)))
#define AS3 __attribute__((address_space(3)))

__device__ __forceinline__ void async16(const void* g, void* l) {
  // global -> LDS direct copy, 16B per lane; LDS dest = wave-uniform base + lane*16
  __builtin_amdgcn_global_load_lds((const AS1 void*)(unsigned long long)(g),
                                   (AS3 void*)(unsigned int)(unsigned long long)(l),
                                   16, 0, 0);
}

__device__ inline unsigned short f2b(float x) {
  unsigned int u = __float_as_uint(x);
  unsigned int r = u + 0x7fffu + ((u >> 16) & 1u);
  return (unsigned short)(r >> 16);
}

// ---------------- prep: softmax(rel_attn), sigmoid(imp) ----------------
__global__ void k_prep(const float* rel, const float* imp, float* rw, float* sig) {
  if (threadIdx.x == 0) {
    float m = -1e30f;
    for (int r = 0; r < RR; r++) m = fmaxf(m, rel[r]);
    float e[RR], s = 0.f;
    for (int r = 0; r < RR; r++) { e[r] = expf(rel[r] - m); s += e[r]; }
    for (int r = 0; r < RR; r++) rw[r] = e[r] / s;
    for (int i = 0; i < 3 * RR; i++) sig[i] = 1.0f / (1.0f + expf(-imp[i]));
  }
}

// ---- single pass over H: row sums -> dvs[r][n] = rw*rsqrt(rw*sum+eps), plus 0/1 bitmask ----
__global__ void k_dvmask(const float* __restrict__ H, const float* __restrict__ rw,
                         float* __restrict__ dvs, unsigned long long* __restrict__ mask) {
  int wave = (blockIdx.x << 2) | (threadIdx.x >> 6);  // = r*NN + n
  int lane = threadIdx.x & 63;
  int r = wave >> 12;
  const float* row = H + (size_t)wave * EE;
  unsigned long long* mrow = mask + (size_t)wave * (EE / 64);
  float s = 0.f;
  for (int j = 0; j < EE / 64; j++) {
    float h = row[j * 64 + lane];
    s += h;
    unsigned long long m = __ballot(h != 0.0f);
    if (lane == 0) mrow[j] = m;
  }
  for (int off = 32; off; off >>= 1) s += __shfl_down(s, off);
  if (lane == 0) {
    float rwr = rw[r];
    dvs[wave] = rwr * rsqrtf(rwr * s + 1e-8f);
  }
}

// ---- column counts via ballot bit-transpose: wave handles 64 rows x one 64-col word ----
__global__ void k_de_pop(const unsigned long long* __restrict__ mask, float* __restrict__ de_acc) {
  int wid = threadIdx.x >> 6, lane = threadIdx.x & 63;
  int wcol = blockIdx.x, r = blockIdx.z;
  int n0 = (blockIdx.y << 8) + (wid << 6);
  unsigned long long w = mask[(size_t)(r * NN + n0 + lane) * (EE / 64) + wcol];
  float cnt = 0.f;
#pragma unroll
  for (int b = 0; b < 64; b++) {
    unsigned long long m = __ballot(((w >> b) & 1ULL) != 0);
    if (lane == b) cnt = (float)__popcll(m);
  }
  atomicAdd(&de_acc[r * EE + (wcol << 6) + lane], cnt);
}

// ---- finalize in place: de[i] = rsqrt(rw*count+eps) ----
__global__ void k_de_fin(const float* __restrict__ rw, float* __restrict__ de) {
  int i = blockIdx.x * 256 + threadIdx.x;
  int r = i / EE;
  de[i] = rsqrtf(rw[r] * de[i] + 1e-8f);
}

// ---- build theta[r][n][e] bf16 and thetaT[r][e][n] from bitmask ----
__global__ void k_build_theta_bits(const unsigned long long* __restrict__ mask,
                                   const float* __restrict__ dvs, const float* __restrict__ de,
                                   unsigned short* __restrict__ theta, unsigned short* __restrict__ thetaT) {
  __shared__ unsigned short tile[64][65];
  int r = blockIdx.z;
  int e0 = blockIdx.x * 64, n0 = blockIdx.y * 64;
  int tr = threadIdx.x >> 4, tc = threadIdx.x & 15;
  float de0 = de[r * EE + e0 + tc * 4 + 0];
  float de1 = de[r * EE + e0 + tc * 4 + 1];
  float de2 = de[r * EE + e0 + tc * 4 + 2];
  float de3 = de[r * EE + e0 + tc * 4 + 3];
  int wcol = e0 >> 6;
#pragma unroll
  for (int i = 0; i < 4; i++) {
    int n = n0 + tr + 16 * i;
    unsigned long long w = mask[((size_t)r * NN + n) * (EE / 64) + wcol];
    float d = dvs[r * NN + n];
    unsigned short b0 = ((w >> (tc * 4 + 0)) & 1) ? f2b(d * de0) : 0;
    unsigned short b1 = ((w >> (tc * 4 + 1)) & 1) ? f2b(d * de1) : 0;
    unsigned short b2 = ((w >> (tc * 4 + 2)) & 1) ? f2b(d * de2) : 0;
    unsigned short b3 = ((w >> (tc * 4 + 3)) & 1) ? f2b(d * de3) : 0;
    ushort4 o; o.x = b0; o.y = b1; o.z = b2; o.w = b3;
    *(ushort4*)(theta + ((size_t)r * NN + n) * EE + e0 + tc * 4) = o;
    tile[tr + 16 * i][tc * 4 + 0] = b0;
    tile[tr + 16 * i][tc * 4 + 1] = b1;
    tile[tr + 16 * i][tc * 4 + 2] = b2;
    tile[tr + 16 * i][tc * 4 + 3] = b3;
  }
  __syncthreads();
#pragma unroll
  for (int i = 0; i < 4; i++) {
    int e = e0 + tr + 16 * i;
    ushort4 o;
    o.x = tile[tc * 4 + 0][tr + 16 * i];
    o.y = tile[tc * 4 + 1][tr + 16 * i];
    o.z = tile[tc * 4 + 2][tr + 16 * i];
    o.w = tile[tc * 4 + 3][tr + 16 * i];
    *(ushort4*)(thetaT + ((size_t)r * EE + e) * NN + n0 + tc * 4) = o;
  }
}

// ---- flat f32 -> bf16 ----
__global__ void k_cvt(const float* __restrict__ src, unsigned short* __restrict__ dst) {
  int i = (blockIdx.x * 256 + threadIdx.x) * 4;
  float4 v = *(const float4*)(src + i);
  ushort4 o; o.x = f2b(v.x); o.y = f2b(v.y); o.z = f2b(v.z); o.w = f2b(v.w);
  *(ushort4*)(dst + i) = o;
}

// ---- f32 [Z][M][C] -> bf16 [Z][C][M] (transpose) ----
__global__ void k_cvtT(const float* __restrict__ src, unsigned short* __restrict__ dst, int M, int C) {
  __shared__ unsigned short tile[64][65];
  int z = blockIdx.z;
  int c0 = blockIdx.x * 64, m0 = blockIdx.y * 64;
  const float* s = src + (size_t)z * M * C;
  unsigned short* d = dst + (size_t)z * M * C;
  int tr = threadIdx.x >> 4, tc = threadIdx.x & 15;
#pragma unroll
  for (int i = 0; i < 4; i++) {
    int m = m0 + tr + 16 * i;
    float4 v = *(const float4*)(s + (size_t)m * C + c0 + tc * 4);
    tile[tr + 16 * i][tc * 4 + 0] = f2b(v.x);
    tile[tr + 16 * i][tc * 4 + 1] = f2b(v.y);
    tile[tr + 16 * i][tc * 4 + 2] = f2b(v.z);
    tile[tr + 16 * i][tc * 4 + 3] = f2b(v.w);
  }
  __syncthreads();
#pragma unroll
  for (int i = 0; i < 4; i++) {
    int c = c0 + tr + 16 * i;
    ushort4 v;
    v.x = tile[tc * 4 + 0][tr + 16 * i];
    v.y = tile[tc * 4 + 1][tr + 16 * i];
    v.z = tile[tc * 4 + 2][tr + 16 * i];
    v.w = tile[tc * 4 + 3][tr + 16 * i];
    *(ushort4*)(d + (size_t)c * M + m0 + tc * 4) = v;
  }
}

// ---- bf16 [M][C] -> bf16 [C][M] ----
__global__ void k_tr(const unsigned short* __restrict__ src, unsigned short* __restrict__ dst, int M, int C) {
  __shared__ unsigned short tile[64][65];
  int c0 = blockIdx.x * 64, m0 = blockIdx.y * 64;
  int tr = threadIdx.x >> 4, tc = threadIdx.x & 15;
#pragma unroll
  for (int i = 0; i < 4; i++) {
    int m = m0 + tr + 16 * i;
    ushort4 v = *(const ushort4*)(src + (size_t)m * C + c0 + tc * 4);
    tile[tr + 16 * i][tc * 4 + 0] = v.x;
    tile[tr + 16 * i][tc * 4 + 1] = v.y;
    tile[tr + 16 * i][tc * 4 + 2] = v.z;
    tile[tr + 16 * i][tc * 4 + 3] = v.w;
  }
  __syncthreads();
#pragma unroll
  for (int i = 0; i < 4; i++) {
    int c = c0 + tr + 16 * i;
    ushort4 v;
    v.x = tile[tc * 4 + 0][tr + 16 * i];
    v.y = tile[tc * 4 + 1][tr + 16 * i];
    v.z = tile[tc * 4 + 2][tr + 16 * i];
    v.w = tile[tc * 4 + 3][tr + 16 * i];
    *(ushort4*)(dst + (size_t)c * M + m0 + tc * 4) = v;
  }
}

// ---- W1catT[o][r*FF+f] = sig*W1[r][f][o] ----
__global__ void k_wcat(const float* __restrict__ W, const float* __restrict__ sig, int loff, int Fin,
                       unsigned short* __restrict__ WT) {
  int idx = blockIdx.x * 256 + threadIdx.x;
  int o = idx % HDD;
  int f = (idx / HDD) % Fin;
  int r = idx / (HDD * Fin);
  WT[(size_t)o * (RR * Fin) + r * Fin + f] = f2b(sig[loff + r] * W[((size_t)r * Fin + f) * HDD + o]);
}

// ---- WT[r][o][c] = sig*W[r][c][o] ----
__global__ void k_wt(const float* __restrict__ W, const float* __restrict__ sig, int loff,
                     int Cin, int Cout, unsigned short* __restrict__ WT) {
  int idx = blockIdx.x * 256 + threadIdx.x;
  int c = idx % Cin;
  int o = (idx / Cin) % Cout;
  int r = idx / (Cin * Cout);
  WT[idx] = f2b(sig[loff + r] * W[((size_t)r * Cin + c) * Cout + o]);
}

// ---------------- MFMA GEMM, 128x128 tile, BK=64, async LDS staging, split-K ----------------
// C[128x128 tile] (+)= A[M x K] * BT[N x K]^T  for z = rz*SK + kz
// LDS k-major: cell(kg,row) at elem kg*1040 + row*8 (16B pad/kgroup -> uniform-bank b128 reads)
// mode 1: atomicAdd f32 (caller memsets C); mode 0: plain store (SK==1 only)
__global__ __launch_bounds__(256) void k_gemm2(
    const unsigned short* __restrict__ A, const unsigned short* __restrict__ BT,
    int K, int lda, int ldb, long a_rs, long b_rs,
    int SK, int mode, float* __restrict__ C, long c_rel, int ldc) {
  __shared__ unsigned short Al[8 * 1040];
  __shared__ unsigned short Bl[8 * 1040];
  int tid = threadIdx.x, wid = tid >> 6, lane = tid & 63;
  int m0 = blockIdx.x << 7, n0 = blockIdx.y << 7;
  int rz = blockIdx.z / SK, kz = blockIdx.z - rz * SK;
  int Kc = K / SK;
  const unsigned short* Ab = A + (size_t)rz * a_rs + (size_t)m0 * lda + (size_t)kz * Kc;
  const unsigned short* Bb = BT + (size_t)rz * b_rs + (size_t)n0 * ldb + (size_t)kz * Kc;
  int wm = (wid >> 1) << 6, wn = (wid & 1) << 6;
  int fm = lane & 15, quad = lane >> 4;
  floatx4 acc[4][4];
#pragma unroll
  for (int i = 0; i < 4; i++)
#pragma unroll
    for (int j = 0; j < 4; j++) acc[i][j] = (floatx4){0.f, 0.f, 0.f, 0.f};
  for (int k0 = 0; k0 < Kc; k0 += 64) {
#pragma unroll
    for (int t = 0; t < 4; t++) {
      int idx = (t << 2) | wid;          // 0..15 covers kg 0..7 x row-half {0,64}
      int kg = idx >> 1, half = (idx & 1) << 6;
      async16(Ab + (size_t)(half + lane) * lda + k0 + kg * 8, &Al[kg * 1040 + half * 8 + lane * 8]);
      async16(Bb + (size_t)(half + lane) * ldb + k0 + kg * 8, &Bl[kg * 1040 + half * 8 + lane * 8]);
    }
    __syncthreads();  // vmcnt(0) drain before s_barrier makes LDS writes visible
#pragma unroll
    for (int ks = 0; ks < 2; ks++) {
      int kgb = ((ks << 2) | quad) * 1040;
      bf16x8 a[4], b[4];
#pragma unroll
      for (int i = 0; i < 4; i++) {
        a[i] = *(const bf16x8*)&Al[kgb + (wm + i * 16 + fm) * 8];
        b[i] = *(const bf16x8*)&Bl[kgb + (wn + i * 16 + fm) * 8];
      }
#pragma unroll
      for (int i = 0; i < 4; i++)
#pragma unroll
        for (int j = 0; j < 4; j++)
          acc[i][j] = __builtin_amdgcn_mfma_f32_16x16x32_bf16(a[i], b[j], acc[i][j], 0, 0, 0);
    }
    __syncthreads();
  }
  float* Cb = C + (size_t)rz * c_rel;
#pragma unroll
  for (int mi = 0; mi < 4; mi++)
#pragma unroll
    for (int ni = 0; ni < 4; ni++)
#pragma unroll
      for (int v = 0; v < 4; v++) {
        int row = m0 + wm + mi * 16 + quad * 4 + v;
        int col = n0 + wn + ni * 16 + fm;
        float* p = Cb + (size_t)row * ldc + col;
        if (mode) atomicAdd(p, acc[mi][ni][v]);
        else *p = acc[mi][ni][v];
      }
}

// ---- column stats over [NN][HDD] f32 ----
__global__ void k_colstats(const float* __restrict__ x, float* __restrict__ cs, float* __restrict__ cs2) {
  int col = threadIdx.x;
  int row0 = blockIdx.y * 64;
  float s = 0.f, s2 = 0.f;
  for (int i = 0; i < 64; i++) {
    float v = x[(size_t)(row0 + i) * HDD + col];
    s += v; s2 += v * v;
  }
  atomicAdd(&cs[col], s);
  atomicAdd(&cs2[col], s2);
}

// ---- BN (batch stats) -> LN -> ELU -> bf16 [NN][HDD] ----
__global__ void k_bnlnelu(const float* __restrict__ x, const float* __restrict__ cs, const float* __restrict__ cs2,
                          const float* __restrict__ bg, const float* __restrict__ bb,
                          const float* __restrict__ lg, const float* __restrict__ lb,
                          unsigned short* __restrict__ out) {
  int wid = threadIdx.x >> 6, lane = threadIdx.x & 63;
  int n = blockIdx.x * 4 + wid;
  float y[4];
  float m = 0.f;
#pragma unroll
  for (int j = 0; j < 4; j++) {
    int c = lane + 64 * j;
    float mu = cs[c] * (1.0f / NN);
    float var = cs2[c] * (1.0f / NN) - mu * mu;
    float xv = x[(size_t)n * HDD + c];
    y[j] = (xv - mu) * rsqrtf(var + 1e-5f) * bg[c] + bb[c];
    m += y[j];
  }
  for (int off = 32; off; off >>= 1) m += __shfl_down(m, off);
  m = __shfl(m, 0) * (1.0f / HDD);
  float var = 0.f;
#pragma unroll
  for (int j = 0; j < 4; j++) { float d = y[j] - m; var += d * d; }
  for (int off = 32; off; off >>= 1) var += __shfl_down(var, off);
  var = __shfl(var, 0) * (1.0f / HDD);
  float inv = rsqrtf(var + 1e-5f);
#pragma unroll
  for (int j = 0; j < 4; j++) {
    int c = lane + 64 * j;
    float z = (y[j] - m) * inv * lg[c] + lb[c];
    z = z > 0.f ? z : expm1f(z);
    out[(size_t)n * HDD + c] = f2b(z);
  }
}

// ---- d_out[n][f] = X[n][f] + b3[f] ----
__global__ void k_initout(const float* __restrict__ X, const float* __restrict__ b3, float* __restrict__ out) {
  int i = (blockIdx.x * 256 + threadIdx.x) * 4;
  float4 x = *(const float4*)(X + i);
  const float* b = b3 + (i & (FF - 1));
  float4 o; o.x = x.x + b[0]; o.y = x.y + b[1]; o.z = x.z + b[2]; o.w = x.w + b[3];
  *(float4*)(out + i) = o;
}

extern "C" void kernel_launch(void* const* d_in, const int* in_sizes, int n_in,
                              void* d_out, int out_size, void* d_ws, size_t ws_size,
                              hipStream_t stream) {
  const float* X   = (const float*)d_in[0];
  const float* H   = (const float*)d_in[1];
  const float* W1  = (const float*)d_in[2];
  const float* W2  = (const float*)d_in[3];
  const float* W3  = (const float*)d_in[4];
  const float* imp = (const float*)d_in[5];
  const float* b3  = (const float*)d_in[8];
  const float* bng = (const float*)d_in[9];
  const float* bnb = (const float*)d_in[10];
  const float* lng = (const float*)d_in[11];
  const float* lnb = (const float*)d_in[12];
  const float* rel = (const float*)d_in[13];
  (void)in_sizes; (void)n_in; (void)out_size; (void)ws_size; (void)imp;

  char* w = (char*)d_ws;
  size_t off = 0;
  auto alloc = [&](size_t bytes) -> void* {
    void* p = w + off;
    off += (bytes + 255) & ~(size_t)255;
    return p;
  };
  float* rw   = (float*)alloc(16);
  float* sig  = (float*)alloc(48);
  float* dvs  = (float*)alloc((size_t)RR * NN * 4);
  float* de   = (float*)alloc((size_t)RR * EE * 4);
  float* cs   = (float*)alloc(HDD * 4);
  float* cs2  = (float*)alloc(HDD * 4);
  unsigned long long* mask = (unsigned long long*)alloc((size_t)RR * NN * (EE / 64) * 8);
  unsigned short* theta  = (unsigned short*)alloc((size_t)RR * NN * EE * 2);
  unsigned short* thetaT = (unsigned short*)alloc((size_t)RR * NN * EE * 2);
  float* bufA = (float*)alloc((size_t)RR * EE * HDD * 4);           // 8MB f32
  float* bufB = (float*)alloc((size_t)RR * EE * HDD * 4);           // 8MB f32
  unsigned short* bufC = (unsigned short*)alloc((size_t)RR * EE * HDD * 2);  // 4MB bf16
  unsigned short* bufD = (unsigned short*)alloc((size_t)RR * EE * HDD * 2);  // 4MB bf16
  float* convout = (float*)alloc((size_t)NN * HDD * 4);             // 4MB
  unsigned short* Xb  = (unsigned short*)alloc((size_t)NN * HDD * 2);
  unsigned short* XbT = (unsigned short*)alloc((size_t)NN * HDD * 2);
  unsigned short* bufW = (unsigned short*)alloc((size_t)RR * HDD * HDD * 2); // 512KB

  // ---- prep ----
  k_prep<<<1, 64, 0, stream>>>(rel, imp, rw, sig);
  k_dvmask<<<(RR * NN) / 4, 256, 0, stream>>>(H, rw, dvs, mask);
  hipMemsetAsync(de, 0, (size_t)RR * EE * 4, stream);
  k_de_pop<<<dim3(EE / 64, NN / 256, RR), 256, 0, stream>>>(mask, de);
  k_de_fin<<<(RR * EE) / 256, 256, 0, stream>>>(rw, de);
  k_build_theta_bits<<<dim3(EE / 64, NN / 64, RR), 256, 0, stream>>>(mask, dvs, de, theta, thetaT);
  k_cvtT<<<dim3(FF / 64, NN / 64, 1), 256, 0, stream>>>(X, XbT, NN, FF);  // XbT = X^T bf16 [128][4096]

  // ---- layer 1 (128 -> 256) ----
  // tT[r][f][e] = sum_n X^T[f][n] thetaT[r][e][n]   (M=128,N=2048,K=4096, SK=8)
  hipMemsetAsync(bufA, 0, (size_t)RR * FF * EE * 4, stream);
  k_gemm2<<<dim3(1, EE / 128, RR * 8), 256, 0, stream>>>(
      XbT, thetaT, NN, NN, NN, 0, (long)EE * NN, 8, 1, bufA, (long)FF * EE, EE);
  k_cvt<<<(RR * FF * EE) / 1024, 256, 0, stream>>>(bufA, bufC);  // tTb
  // Hcat[n][r*128+f] = sum_e theta[r][n][e] tTb[r][f][e]   (M=4096,N=128,K=2048, SK=4)
  hipMemsetAsync(bufB, 0, (size_t)NN * RR * FF * 4, stream);
  k_gemm2<<<dim3(NN / 128, 1, RR * 4), 256, 0, stream>>>(
      theta, bufC, EE, EE, EE, (long)NN * EE, (long)FF * EE, 4, 1, bufB, (long)FF, RR * FF);
  k_cvt<<<(NN * RR * FF) / 1024, 256, 0, stream>>>(bufB, bufD);  // Hcatb
  k_wcat<<<(RR * FF * HDD) / 256, 256, 0, stream>>>(W1, sig, 0, FF, bufW);
  // convout = Hcatb @ W1cat  (M=4096,N=256,K=512, SK=4; b1 dropped: BN-invariant)
  hipMemsetAsync(convout, 0, (size_t)NN * HDD * 4, stream);
  k_gemm2<<<dim3(NN / 128, HDD / 128, 4), 256, 0, stream>>>(
      bufD, bufW, RR * FF, RR * FF, RR * FF, 0, 0, 4, 1, convout, 0, HDD);
  hipMemsetAsync(cs, 0, HDD * 4, stream);
  hipMemsetAsync(cs2, 0, HDD * 4, stream);
  k_colstats<<<dim3(1, NN / 64), 256, 0, stream>>>(convout, cs, cs2);
  k_bnlnelu<<<NN / 4, 256, 0, stream>>>(convout, cs, cs2, bng, bnb, lng, lnb, Xb);
  k_tr<<<dim3(HDD / 64, NN / 64), 256, 0, stream>>>(Xb, XbT, NN, HDD);

  // ---- layer 2 (256 -> 256) ----
  // t[r][e][c] = sum_n thetaT[r][e][n] h^T[c][n]   (M=2048,N=256,K=4096, SK=8)
  hipMemsetAsync(bufA, 0, (size_t)RR * EE * HDD * 4, stream);
  k_gemm2<<<dim3(EE / 128, HDD / 128, RR * 8), 256, 0, stream>>>(
      thetaT, XbT, NN, NN, NN, (long)EE * NN, 0, 8, 1, bufA, (long)EE * HDD, HDD);
  k_cvt<<<(RR * EE * HDD) / 1024, 256, 0, stream>>>(bufA, bufD);  // t2b [r][e][c]
  k_wt<<<(RR * HDD * HDD) / 256, 256, 0, stream>>>(W2, sig, RR, HDD, HDD, bufW);  // W2T [r][o][c]
  // u[r][e][o] = sum_c t2b[r][e][c] W2T[r][o][c]   (M=2048,N=256,K=256, SK=2)
  hipMemsetAsync(bufB, 0, (size_t)RR * EE * HDD * 4, stream);
  k_gemm2<<<dim3(EE / 128, HDD / 128, RR * 2), 256, 0, stream>>>(
      bufD, bufW, HDD, HDD, HDD, (long)EE * HDD, (long)HDD * HDD, 2, 1, bufB, (long)EE * HDD, HDD);
  k_cvtT<<<dim3(HDD / 64, EE / 64, RR), 256, 0, stream>>>(bufB, bufC, EE, HDD);  // uTb [r][o][e]
  // convout[n][o] = sum_r sum_e theta[r][n][e] uTb[r][o][e]   (M=4096,N=256,K=2048, rel-fused, SK=2)
  hipMemsetAsync(convout, 0, (size_t)NN * HDD * 4, stream);
  k_gemm2<<<dim3(NN / 128, HDD / 128, RR * 2), 256, 0, stream>>>(
      theta, bufC, EE, EE, EE, (long)NN * EE, (long)HDD * EE, 2, 1, convout, 0, HDD);
  hipMemsetAsync(cs, 0, HDD * 4, stream);
  hipMemsetAsync(cs2, 0, HDD * 4, stream);
  k_colstats<<<dim3(1, NN / 64), 256, 0, stream>>>(convout, cs, cs2);
  k_bnlnelu<<<NN / 4, 256, 0, stream>>>(convout, cs, cs2, bng + HDD, bnb + HDD, lng + HDD, lnb + HDD, Xb);

  // ---- layer 3 (256 -> 128), W3 applied first ----
  k_wt<<<(RR * HDD * FF) / 256, 256, 0, stream>>>(W3, sig, 2 * RR, HDD, FF, bufW);  // W3T [r][o][c]
  // y[r][n][o] = sum_c Xb[n][c] W3T[r][o][c]   (M=4096,N=128,K=256, SK=2)
  hipMemsetAsync(bufA, 0, (size_t)RR * NN * FF * 4, stream);
  k_gemm2<<<dim3(NN / 128, 1, RR * 2), 256, 0, stream>>>(
      Xb, bufW, HDD, HDD, HDD, 0, (long)FF * HDD, 2, 1, bufA, (long)NN * FF, FF);
  k_cvtT<<<dim3(FF / 64, NN / 64, RR), 256, 0, stream>>>(bufA, bufD, NN, FF);  // yTb [r][f][n]
  // s[r][e][f] = sum_n thetaT[r][e][n] yTb[r][f][n]   (M=2048,N=128,K=4096, SK=8)
  hipMemsetAsync(bufB, 0, (size_t)RR * EE * FF * 4, stream);
  k_gemm2<<<dim3(EE / 128, 1, RR * 8), 256, 0, stream>>>(
      thetaT, bufD, NN, NN, NN, (long)EE * NN, (long)FF * NN, 8, 1, bufB, (long)EE * FF, FF);
  k_cvtT<<<dim3(FF / 64, EE / 64, RR), 256, 0, stream>>>(bufB, bufC, EE, FF);  // sTb [r][f][e]
  k_initout<<<(NN * FF) / 1024, 256, 0, stream>>>(X, b3, (float*)d_out);
  // d_out[n][f] += sum_r sum_e theta[r][n][e] sTb[r][f][e]   (M=4096,N=128,K=2048, rel-fused, SK=4)
  k_gemm2<<<dim3(NN / 128, 1, RR * 4), 256, 0, stream>>>(
      theta, bufC, EE, EE, EE, (long)NN * EE, (long)FF * EE, 4, 1, (float*)d_out, 0, FF);
}

// Round 4
// 601.539 us; speedup vs baseline: 1.3658x; 1.2131x over previous
//
#include <hip/hip_runtime.h>
#include <hip/hip_bf16.h>

#define NN 4096
#define EE 2048
#define RR 4
#define FF 128
#define HDD 256

typedef __attribute__((ext_vector_type(4))) float floatx4;
typedef __attribute__((ext_vector_type(8))) __bf16 bf16x8;

#define AS1 __attribute__((address_space(1)))
#define AS3 __attribute__((address_space(3)))

__device__ __forceinline__ void async16(const void* g, void* l) {
  // global -> LDS direct copy, 16B per lane; LDS dest = wave-uniform base + lane*16
  __builtin_amdgcn_global_load_lds((const AS1 void*)(unsigned long long)(g),
                                   (AS3 void*)(unsigned int)(unsigned long long)(l),
                                   16, 0, 0);
}

__device__ inline unsigned short f2b(float x) {
  unsigned int u = __float_as_uint(x);
  unsigned int r = u + 0x7fffu + ((u >> 16) & 1u);
  return (unsigned short)(r >> 16);
}

// ---------------- prep: softmax(rel_attn), sigmoid(imp) ----------------
__global__ void k_prep(const float* rel, const float* imp, float* rw, float* sig) {
  if (threadIdx.x == 0) {
    float m = -1e30f;
    for (int r = 0; r < RR; r++) m = fmaxf(m, rel[r]);
    float e[RR], s = 0.f;
    for (int r = 0; r < RR; r++) { e[r] = expf(rel[r] - m); s += e[r]; }
    for (int r = 0; r < RR; r++) rw[r] = e[r] / s;
    for (int i = 0; i < 3 * RR; i++) sig[i] = 1.0f / (1.0f + expf(-imp[i]));
  }
}

// ---- single pass over H: row sums -> dvs[r][n] = rw*rsqrt(rw*sum+eps), plus 0/1 bitmask ----
__global__ void k_dvmask(const float* __restrict__ H, const float* __restrict__ rw,
                         float* __restrict__ dvs, unsigned long long* __restrict__ mask) {
  int wave = (blockIdx.x << 2) | (threadIdx.x >> 6);  // = r*NN + n
  int lane = threadIdx.x & 63;
  int r = wave >> 12;
  const float* row = H + (size_t)wave * EE;
  unsigned long long* mrow = mask + (size_t)wave * (EE / 64);
  float s = 0.f;
  for (int j = 0; j < EE / 64; j++) {
    float h = row[j * 64 + lane];
    s += h;
    unsigned long long m = __ballot(h != 0.0f);
    if (lane == 0) mrow[j] = m;
  }
  for (int off = 32; off; off >>= 1) s += __shfl_down(s, off);
  if (lane == 0) {
    float rwr = rw[r];
    dvs[wave] = rwr * rsqrtf(rwr * s + 1e-8f);
  }
}

// ---- column counts via ballot bit-transpose: wave handles 64 rows x one 64-col word ----
__global__ void k_de_pop(const unsigned long long* __restrict__ mask, float* __restrict__ de_acc) {
  int wid = threadIdx.x >> 6, lane = threadIdx.x & 63;
  int wcol = blockIdx.x, r = blockIdx.z;
  int n0 = (blockIdx.y << 8) + (wid << 6);
  unsigned long long w = mask[(size_t)(r * NN + n0 + lane) * (EE / 64) + wcol];
  float cnt = 0.f;
#pragma unroll
  for (int b = 0; b < 64; b++) {
    unsigned long long m = __ballot(((w >> b) & 1ULL) != 0);
    if (lane == b) cnt = (float)__popcll(m);
  }
  atomicAdd(&de_acc[r * EE + (wcol << 6) + lane], cnt);
}

// ---- finalize in place: de[i] = rsqrt(rw*count+eps) ----
__global__ void k_de_fin(const float* __restrict__ rw, float* __restrict__ de) {
  int i = blockIdx.x * 256 + threadIdx.x;
  int r = i / EE;
  de[i] = rsqrtf(rw[r] * de[i] + 1e-8f);
}

// ---- build theta[r][n][e] bf16 and thetaT[r][e][n] from bitmask ----
__global__ void k_build_theta_bits(const unsigned long long* __restrict__ mask,
                                   const float* __restrict__ dvs, const float* __restrict__ de,
                                   unsigned short* __restrict__ theta, unsigned short* __restrict__ thetaT) {
  __shared__ unsigned short tile[64][65];
  int r = blockIdx.z;
  int e0 = blockIdx.x * 64, n0 = blockIdx.y * 64;
  int tr = threadIdx.x >> 4, tc = threadIdx.x & 15;
  float de0 = de[r * EE + e0 + tc * 4 + 0];
  float de1 = de[r * EE + e0 + tc * 4 + 1];
  float de2 = de[r * EE + e0 + tc * 4 + 2];
  float de3 = de[r * EE + e0 + tc * 4 + 3];
  int wcol = e0 >> 6;
#pragma unroll
  for (int i = 0; i < 4; i++) {
    int n = n0 + tr + 16 * i;
    unsigned long long w = mask[((size_t)r * NN + n) * (EE / 64) + wcol];
    float d = dvs[r * NN + n];
    unsigned short b0 = ((w >> (tc * 4 + 0)) & 1) ? f2b(d * de0) : 0;
    unsigned short b1 = ((w >> (tc * 4 + 1)) & 1) ? f2b(d * de1) : 0;
    unsigned short b2 = ((w >> (tc * 4 + 2)) & 1) ? f2b(d * de2) : 0;
    unsigned short b3 = ((w >> (tc * 4 + 3)) & 1) ? f2b(d * de3) : 0;
    ushort4 o; o.x = b0; o.y = b1; o.z = b2; o.w = b3;
    *(ushort4*)(theta + ((size_t)r * NN + n) * EE + e0 + tc * 4) = o;
    tile[tr + 16 * i][tc * 4 + 0] = b0;
    tile[tr + 16 * i][tc * 4 + 1] = b1;
    tile[tr + 16 * i][tc * 4 + 2] = b2;
    tile[tr + 16 * i][tc * 4 + 3] = b3;
  }
  __syncthreads();
#pragma unroll
  for (int i = 0; i < 4; i++) {
    int e = e0 + tr + 16 * i;
    ushort4 o;
    o.x = tile[tc * 4 + 0][tr + 16 * i];
    o.y = tile[tc * 4 + 1][tr + 16 * i];
    o.z = tile[tc * 4 + 2][tr + 16 * i];
    o.w = tile[tc * 4 + 3][tr + 16 * i];
    *(ushort4*)(thetaT + ((size_t)r * EE + e) * NN + n0 + tc * 4) = o;
  }
}

// ---- f32 [M][C] -> bf16 [C][M] (transpose+convert), z=1 use ----
__global__ void k_cvtT(const float* __restrict__ src, unsigned short* __restrict__ dst, int M, int C) {
  __shared__ unsigned short tile[64][65];
  int c0 = blockIdx.x * 64, m0 = blockIdx.y * 64;
  int tr = threadIdx.x >> 4, tc = threadIdx.x & 15;
#pragma unroll
  for (int i = 0; i < 4; i++) {
    int m = m0 + tr + 16 * i;
    float4 v = *(const float4*)(src + (size_t)m * C + c0 + tc * 4);
    tile[tr + 16 * i][tc * 4 + 0] = f2b(v.x);
    tile[tr + 16 * i][tc * 4 + 1] = f2b(v.y);
    tile[tr + 16 * i][tc * 4 + 2] = f2b(v.z);
    tile[tr + 16 * i][tc * 4 + 3] = f2b(v.w);
  }
  __syncthreads();
#pragma unroll
  for (int i = 0; i < 4; i++) {
    int c = c0 + tr + 16 * i;
    ushort4 v;
    v.x = tile[tc * 4 + 0][tr + 16 * i];
    v.y = tile[tc * 4 + 1][tr + 16 * i];
    v.z = tile[tc * 4 + 2][tr + 16 * i];
    v.w = tile[tc * 4 + 3][tr + 16 * i];
    *(ushort4*)(dst + (size_t)c * M + m0 + tc * 4) = v;
  }
}

// ---- bf16 [z][M][C] -> bf16 [z][C][M] ----
__global__ void k_trz(const unsigned short* __restrict__ src, unsigned short* __restrict__ dst, int M, int C) {
  __shared__ unsigned short tile[64][65];
  int z = blockIdx.z;
  int c0 = blockIdx.x * 64, m0 = blockIdx.y * 64;
  const unsigned short* s = src + (size_t)z * M * C;
  unsigned short* d = dst + (size_t)z * M * C;
  int tr = threadIdx.x >> 4, tc = threadIdx.x & 15;
#pragma unroll
  for (int i = 0; i < 4; i++) {
    int m = m0 + tr + 16 * i;
    ushort4 v = *(const ushort4*)(s + (size_t)m * C + c0 + tc * 4);
    tile[tr + 16 * i][tc * 4 + 0] = v.x;
    tile[tr + 16 * i][tc * 4 + 1] = v.y;
    tile[tr + 16 * i][tc * 4 + 2] = v.z;
    tile[tr + 16 * i][tc * 4 + 3] = v.w;
  }
  __syncthreads();
#pragma unroll
  for (int i = 0; i < 4; i++) {
    int c = c0 + tr + 16 * i;
    ushort4 v;
    v.x = tile[tc * 4 + 0][tr + 16 * i];
    v.y = tile[tc * 4 + 1][tr + 16 * i];
    v.z = tile[tc * 4 + 2][tr + 16 * i];
    v.w = tile[tc * 4 + 3][tr + 16 * i];
    *(ushort4*)(d + (size_t)c * M + m0 + tc * 4) = v;
  }
}

// ---- W1catT[o][r*FF+f] = sig*W1[r][f][o] ----
__global__ void k_wcat(const float* __restrict__ W, const float* __restrict__ sig, int loff, int Fin,
                       unsigned short* __restrict__ WT) {
  int idx = blockIdx.x * 256 + threadIdx.x;
  int o = idx % HDD;
  int f = (idx / HDD) % Fin;
  int r = idx / (HDD * Fin);
  WT[(size_t)o * (RR * Fin) + r * Fin + f] = f2b(sig[loff + r] * W[((size_t)r * Fin + f) * HDD + o]);
}

// ---- WT[r][o][c] = sig*W[r][c][o] ----
__global__ void k_wt(const float* __restrict__ W, const float* __restrict__ sig, int loff,
                     int Cin, int Cout, unsigned short* __restrict__ WT) {
  int idx = blockIdx.x * 256 + threadIdx.x;
  int c = idx % Cin;
  int o = (idx / Cin) % Cout;
  int r = idx / (Cin * Cout);
  WT[idx] = f2b(sig[loff + r] * W[((size_t)r * Cin + c) * Cout + o]);
}

// ---------------- MFMA GEMM, 128x128 tile, BK=64, async staging, partial-store split-K ----------------
// z = zr*SK + kz. Partial: P[z][M_tile-region], plain f32 stores (NO atomics).
// A base = A + zr*a_rs + m0*lda + kz*(K/SK); B base = BT + zr*b_rs + n0*ldb + kz*(K/SK)
__global__ __launch_bounds__(256) void k_gemm3(
    const unsigned short* __restrict__ A, const unsigned short* __restrict__ BT,
    int K, int SK, int lda, int ldb, long a_rs, long b_rs,
    float* __restrict__ P, long c_ps, int ldc) {
  __shared__ unsigned short Al[8 * 1040];
  __shared__ unsigned short Bl[8 * 1040];
  int tid = threadIdx.x, wid = tid >> 6, lane = tid & 63;
  int m0 = blockIdx.x << 7, n0 = blockIdx.y << 7;
  int z = blockIdx.z, zr = z / SK, kz = z - zr * SK;
  int Kc = K / SK;
  const unsigned short* Ab = A + (size_t)zr * a_rs + (size_t)m0 * lda + (size_t)kz * Kc;
  const unsigned short* Bb = BT + (size_t)zr * b_rs + (size_t)n0 * ldb + (size_t)kz * Kc;
  int wm = (wid >> 1) << 6, wn = (wid & 1) << 6;
  int fm = lane & 15, quad = lane >> 4;
  floatx4 acc[4][4];
#pragma unroll
  for (int i = 0; i < 4; i++)
#pragma unroll
    for (int j = 0; j < 4; j++) acc[i][j] = (floatx4){0.f, 0.f, 0.f, 0.f};
  for (int k0 = 0; k0 < Kc; k0 += 64) {
#pragma unroll
    for (int t = 0; t < 4; t++) {
      int idx = (t << 2) | wid;          // 0..15 covers kg 0..7 x row-half {0,64}
      int kg = idx >> 1, half = (idx & 1) << 6;
      async16(Ab + (size_t)(half + lane) * lda + k0 + kg * 8, &Al[kg * 1040 + half * 8 + lane * 8]);
      async16(Bb + (size_t)(half + lane) * ldb + k0 + kg * 8, &Bl[kg * 1040 + half * 8 + lane * 8]);
    }
    __syncthreads();  // vmcnt(0) drain before s_barrier makes LDS writes visible
#pragma unroll
    for (int ks = 0; ks < 2; ks++) {
      int kgb = ((ks << 2) | quad) * 1040;
      bf16x8 a[4], b[4];
#pragma unroll
      for (int i = 0; i < 4; i++) {
        a[i] = *(const bf16x8*)&Al[kgb + (wm + i * 16 + fm) * 8];
        b[i] = *(const bf16x8*)&Bl[kgb + (wn + i * 16 + fm) * 8];
      }
#pragma unroll
      for (int i = 0; i < 4; i++)
#pragma unroll
        for (int j = 0; j < 4; j++)
          acc[i][j] = __builtin_amdgcn_mfma_f32_16x16x32_bf16(a[i], b[j], acc[i][j], 0, 0, 0);
    }
    __syncthreads();
  }
  float* Cb = P + (size_t)z * c_ps;
#pragma unroll
  for (int mi = 0; mi < 4; mi++)
#pragma unroll
    for (int ni = 0; ni < 4; ni++)
#pragma unroll
      for (int v = 0; v < 4; v++) {
        int row = m0 + wm + mi * 16 + quad * 4 + v;
        int col = n0 + wn + ni * 16 + fm;
        Cb[(size_t)row * ldc + col] = acc[mi][ni][v];
      }
}

// ---- reduce SK partials per zr -> bf16 out[zr][region] ----
__global__ void k_red_bf16(const float* __restrict__ P, unsigned short* __restrict__ out,
                           int SK, long region) {
  long i = ((long)blockIdx.x * 256 + threadIdx.x) * 4;
  int zr = blockIdx.y;
  const float* p = P + (size_t)zr * SK * region + i;
  float4 s = *(const float4*)p;
  for (int k = 1; k < SK; k++) {
    float4 v = *(const float4*)(p + (size_t)k * region);
    s.x += v.x; s.y += v.y; s.z += v.z; s.w += v.w;
  }
  ushort4 o; o.x = f2b(s.x); o.y = f2b(s.y); o.z = f2b(s.z); o.w = f2b(s.w);
  *(ushort4*)(out + (size_t)zr * region + i) = o;
}

// ---- reduce SK partials per r of [NN][FF] -> Hcat[n][r*FF+f] bf16 ----
__global__ void k_red_hcat(const float* __restrict__ P, unsigned short* __restrict__ out, int SK) {
  long i = ((long)blockIdx.x * 256 + threadIdx.x) * 4;
  int r = blockIdx.y;
  const float* p = P + (size_t)r * SK * (NN * FF) + i;
  float4 s = *(const float4*)p;
  for (int k = 1; k < SK; k++) {
    float4 v = *(const float4*)(p + (size_t)k * (NN * FF));
    s.x += v.x; s.y += v.y; s.z += v.z; s.w += v.w;
  }
  long n = i >> 7;
  int f = (int)(i & 127);
  ushort4 o; o.x = f2b(s.x); o.y = f2b(s.y); o.z = f2b(s.z); o.w = f2b(s.w);
  *(ushort4*)(out + n * (RR * FF) + r * FF + f) = o;
}

// ---- reduce ALL Z partials (rel+K fused) -> f32 out ----
__global__ void k_red_f32(const float* __restrict__ P, float* __restrict__ out, int Z, long region) {
  long i = ((long)blockIdx.x * 256 + threadIdx.x) * 4;
  float4 s = *(const float4*)(P + i);
  for (int z = 1; z < Z; z++) {
    float4 v = *(const float4*)(P + (size_t)z * region + i);
    s.x += v.x; s.y += v.y; s.z += v.z; s.w += v.w;
  }
  *(float4*)(out + i) = s;
}

// ---- final: d_out = X + b3 + sum_Z P ----
__global__ void k_red_out(const float* __restrict__ P, const float* __restrict__ X,
                          const float* __restrict__ b3, float* __restrict__ out, int Z) {
  long i = ((long)blockIdx.x * 256 + threadIdx.x) * 4;
  int f = (int)(i & 127);
  float4 s = *(const float4*)(X + i);
  s.x += b3[f]; s.y += b3[f + 1]; s.z += b3[f + 2]; s.w += b3[f + 3];
  for (int z = 0; z < Z; z++) {
    float4 v = *(const float4*)(P + (size_t)z * (NN * FF) + i);
    s.x += v.x; s.y += v.y; s.z += v.z; s.w += v.w;
  }
  *(float4*)(out + i) = s;
}

// ---- column stats over [NN][HDD] f32 ----
__global__ void k_colstats(const float* __restrict__ x, float* __restrict__ cs, float* __restrict__ cs2) {
  int col = threadIdx.x;
  int row0 = blockIdx.y * 64;
  float s = 0.f, s2 = 0.f;
  for (int i = 0; i < 64; i++) {
    float v = x[(size_t)(row0 + i) * HDD + col];
    s += v; s2 += v * v;
  }
  atomicAdd(&cs[col], s);
  atomicAdd(&cs2[col], s2);
}

// ---- BN (batch stats) -> LN -> ELU -> bf16 [NN][HDD] ----
__global__ void k_bnlnelu(const float* __restrict__ x, const float* __restrict__ cs, const float* __restrict__ cs2,
                          const float* __restrict__ bg, const float* __restrict__ bb,
                          const float* __restrict__ lg, const float* __restrict__ lb,
                          unsigned short* __restrict__ out) {
  int wid = threadIdx.x >> 6, lane = threadIdx.x & 63;
  int n = blockIdx.x * 4 + wid;
  float y[4];
  float m = 0.f;
#pragma unroll
  for (int j = 0; j < 4; j++) {
    int c = lane + 64 * j;
    float mu = cs[c] * (1.0f / NN);
    float var = cs2[c] * (1.0f / NN) - mu * mu;
    float xv = x[(size_t)n * HDD + c];
    y[j] = (xv - mu) * rsqrtf(var + 1e-5f) * bg[c] + bb[c];
    m += y[j];
  }
  for (int off = 32; off; off >>= 1) m += __shfl_down(m, off);
  m = __shfl(m, 0) * (1.0f / HDD);
  float var = 0.f;
#pragma unroll
  for (int j = 0; j < 4; j++) { float d = y[j] - m; var += d * d; }
  for (int off = 32; off; off >>= 1) var += __shfl_down(var, off);
  var = __shfl(var, 0) * (1.0f / HDD);
  float inv = rsqrtf(var + 1e-5f);
#pragma unroll
  for (int j = 0; j < 4; j++) {
    int c = lane + 64 * j;
    float z = (y[j] - m) * inv * lg[c] + lb[c];
    z = z > 0.f ? z : expm1f(z);
    out[(size_t)n * HDD + c] = f2b(z);
  }
}

extern "C" void kernel_launch(void* const* d_in, const int* in_sizes, int n_in,
                              void* d_out, int out_size, void* d_ws, size_t ws_size,
                              hipStream_t stream) {
  const float* X   = (const float*)d_in[0];
  const float* H   = (const float*)d_in[1];
  const float* W1  = (const float*)d_in[2];
  const float* W2  = (const float*)d_in[3];
  const float* W3  = (const float*)d_in[4];
  const float* imp = (const float*)d_in[5];
  const float* b3  = (const float*)d_in[8];
  const float* bng = (const float*)d_in[9];
  const float* bnb = (const float*)d_in[10];
  const float* lng = (const float*)d_in[11];
  const float* lnb = (const float*)d_in[12];
  const float* rel = (const float*)d_in[13];
  (void)in_sizes; (void)n_in; (void)out_size; (void)ws_size;

  char* w = (char*)d_ws;
  size_t off = 0;
  auto alloc = [&](size_t bytes) -> void* {
    void* p = w + off;
    off += (bytes + 255) & ~(size_t)255;
    return p;
  };
  float* rw   = (float*)alloc(16);
  float* sig  = (float*)alloc(48);
  float* dvs  = (float*)alloc((size_t)RR * NN * 4);
  float* de   = (float*)alloc((size_t)RR * EE * 4);
  float* cs   = (float*)alloc(HDD * 4);
  float* cs2  = (float*)alloc(HDD * 4);
  unsigned long long* mask = (unsigned long long*)alloc((size_t)RR * NN * (EE / 64) * 8);
  unsigned short* theta  = (unsigned short*)alloc((size_t)RR * NN * EE * 2);   // 64MB
  unsigned short* thetaT = (unsigned short*)alloc((size_t)RR * NN * EE * 2);   // 64MB
  float* bufP = (float*)alloc((size_t)8 * NN * HDD * 4);                       // 32MB partials
  unsigned short* bufC = (unsigned short*)alloc((size_t)RR * EE * HDD * 2);    // 4MB bf16
  unsigned short* bufD = (unsigned short*)alloc((size_t)RR * EE * HDD * 2);    // 4MB bf16
  unsigned short* bufE = (unsigned short*)alloc((size_t)RR * EE * HDD * 2);    // 4MB bf16
  float* convout = (float*)alloc((size_t)NN * HDD * 4);                        // 4MB
  unsigned short* Xb  = (unsigned short*)alloc((size_t)NN * HDD * 2);
  unsigned short* XbT = (unsigned short*)alloc((size_t)NN * HDD * 2);
  unsigned short* bufW = (unsigned short*)alloc((size_t)RR * HDD * HDD * 2);   // 512KB

  // ---- prep ----
  k_prep<<<1, 64, 0, stream>>>(rel, imp, rw, sig);
  k_dvmask<<<(RR * NN) / 4, 256, 0, stream>>>(H, rw, dvs, mask);
  hipMemsetAsync(de, 0, (size_t)RR * EE * 4, stream);
  k_de_pop<<<dim3(EE / 64, NN / 256, RR), 256, 0, stream>>>(mask, de);
  k_de_fin<<<(RR * EE) / 256, 256, 0, stream>>>(rw, de);
  k_build_theta_bits<<<dim3(EE / 64, NN / 64, RR), 256, 0, stream>>>(mask, dvs, de, theta, thetaT);
  k_cvtT<<<dim3(FF / 64, NN / 64), 256, 0, stream>>>(X, XbT, NN, FF);  // XbT [128][4096] bf16

  // ---- layer 1 (128 -> 256) ----
  // tT[r][f][e] = sum_n XbT[f][n] thetaT[r][e][n]   M=128,N=2048,K=4096, z=(r,kz) SK=8 -> 512 blocks
  k_gemm3<<<dim3(1, EE / 128, RR * 8), 256, 0, stream>>>(
      XbT, thetaT, NN, 8, NN, NN, 0, (long)EE * NN, bufP, (long)FF * EE, EE);
  k_red_bf16<<<dim3((FF * EE) / 1024, RR), 256, 0, stream>>>(bufP, bufC, 8, (long)FF * EE);  // tTb
  // Hcat[n][r*128+f] = sum_e theta[r][n][e] tTb[r][f][e]   M=4096,N=128,K=2048, SK=2 -> 256 blocks
  k_gemm3<<<dim3(NN / 128, 1, RR * 2), 256, 0, stream>>>(
      theta, bufC, EE, 2, EE, EE, (long)NN * EE, (long)FF * EE, bufP, (long)NN * FF, FF);
  k_red_hcat<<<dim3((NN * FF) / 1024, RR), 256, 0, stream>>>(bufP, bufD, 2);  // Hcatb [4096][512]
  k_wcat<<<(RR * FF * HDD) / 256, 256, 0, stream>>>(W1, sig, 0, FF, bufW);
  // convout = Hcatb @ W1cat   M=4096,N=256,K=512, SK=4 -> 256 blocks (b1 dropped: BN-invariant)
  k_gemm3<<<dim3(NN / 128, HDD / 128, 4), 256, 0, stream>>>(
      bufD, bufW, RR * FF, 4, RR * FF, RR * FF, 0, 0, bufP, (long)NN * HDD, HDD);
  k_red_f32<<<(NN * HDD) / 1024, 256, 0, stream>>>(bufP, convout, 4, (long)NN * HDD);
  hipMemsetAsync(cs, 0, HDD * 4, stream);
  hipMemsetAsync(cs2, 0, HDD * 4, stream);
  k_colstats<<<dim3(1, NN / 64), 256, 0, stream>>>(convout, cs, cs2);
  k_bnlnelu<<<NN / 4, 256, 0, stream>>>(convout, cs, cs2, bng, bnb, lng, lnb, Xb);
  k_trz<<<dim3(HDD / 64, NN / 64, 1), 256, 0, stream>>>(Xb, XbT, NN, HDD);

  // ---- layer 2 (256 -> 256) ----
  // t2[re][c] = sum_n thetaT-flat[re][n] h^T[c][n]   M=8192,N=256,K=4096, SK=4 -> 512 blocks
  k_gemm3<<<dim3(64, HDD / 128, 4), 256, 0, stream>>>(
      thetaT, XbT, NN, 4, NN, NN, 0, 0, bufP, (long)RR * EE * HDD, HDD);
  k_red_bf16<<<dim3((RR * EE * HDD) / 1024, 1), 256, 0, stream>>>(bufP, bufD, 4, (long)RR * EE * HDD);  // t2b
  k_wt<<<(RR * HDD * HDD) / 256, 256, 0, stream>>>(W2, sig, RR, HDD, HDD, bufW);  // W2T [r][o][c]
  // u[r][e][o] = sum_c t2b[r][e][c] W2T[r][o][c]   M=2048,N=256,K=256, SK=2 -> 256 blocks
  k_gemm3<<<dim3(EE / 128, HDD / 128, RR * 2), 256, 0, stream>>>(
      bufD, bufW, HDD, 2, HDD, HDD, (long)EE * HDD, (long)HDD * HDD, bufP, (long)EE * HDD, HDD);
  k_red_bf16<<<dim3((EE * HDD) / 1024, RR), 256, 0, stream>>>(bufP, bufC, 2, (long)EE * HDD);  // u
  k_trz<<<dim3(HDD / 64, EE / 64, RR), 256, 0, stream>>>(bufC, bufE, EE, HDD);  // uTb [r][o][e]
  // convout[n][o] = sum_r sum_e theta[r][n][e] uTb[r][o][e]   M=4096,N=256,K=2048, z=(r,kz) SK=2 -> 512 blocks
  k_gemm3<<<dim3(NN / 128, HDD / 128, RR * 2), 256, 0, stream>>>(
      theta, bufE, EE, 2, EE, EE, (long)NN * EE, (long)HDD * EE, bufP, (long)NN * HDD, HDD);
  k_red_f32<<<(NN * HDD) / 1024, 256, 0, stream>>>(bufP, convout, 8, (long)NN * HDD);
  hipMemsetAsync(cs, 0, HDD * 4, stream);
  hipMemsetAsync(cs2, 0, HDD * 4, stream);
  k_colstats<<<dim3(1, NN / 64), 256, 0, stream>>>(convout, cs, cs2);
  k_bnlnelu<<<NN / 4, 256, 0, stream>>>(convout, cs, cs2, bng + HDD, bnb + HDD, lng + HDD, lnb + HDD, Xb);

  // ---- layer 3 (256 -> 128), W3 applied first ----
  k_wt<<<(RR * HDD * FF) / 256, 256, 0, stream>>>(W3, sig, 2 * RR, HDD, FF, bufW);  // W3T [r][o][c]
  // y[r][n][o] = sum_c Xb[n][c] W3T[r][o][c]   M=4096,N=128,K=256, SK=2 -> 256 blocks
  k_gemm3<<<dim3(NN / 128, 1, RR * 2), 256, 0, stream>>>(
      Xb, bufW, HDD, 2, HDD, HDD, 0, (long)FF * HDD, bufP, (long)NN * FF, FF);
  k_red_bf16<<<dim3((NN * FF) / 1024, RR), 256, 0, stream>>>(bufP, bufC, 2, (long)NN * FF);  // y [r][n][o]
  k_trz<<<dim3(FF / 64, NN / 64, RR), 256, 0, stream>>>(bufC, bufD, NN, FF);  // yTb [r][f][n]
  // s[r][e][f] = sum_n thetaT[r][e][n] yTb[r][f][n]   M=2048,N=128,K=4096, SK=4 -> 256 blocks
  k_gemm3<<<dim3(EE / 128, 1, RR * 4), 256, 0, stream>>>(
      thetaT, bufD, NN, 4, NN, NN, (long)EE * NN, (long)FF * NN, bufP, (long)EE * FF, FF);
  k_red_bf16<<<dim3((EE * FF) / 1024, RR), 256, 0, stream>>>(bufP, bufC, 4, (long)EE * FF);  // s [r][e][f]
  k_trz<<<dim3(FF / 64, EE / 64, RR), 256, 0, stream>>>(bufC, bufE, EE, FF);  // sTb [r][f][e]
  // P[z] = theta[r] @ sTb[r] chunks   M=4096,N=128,K=2048, z=(r,kz) SK=2 -> 256 blocks
  k_gemm3<<<dim3(NN / 128, 1, RR * 2), 256, 0, stream>>>(
      theta, bufE, EE, 2, EE, EE, (long)NN * EE, (long)FF * EE, bufP, (long)NN * FF, FF);
  // d_out = X + b3 + sum_z P[z]
  k_red_out<<<(NN * FF) / 1024, 256, 0, stream>>>(bufP, X, b3, (float*)d_out, 8);
}